// Round 8
// baseline (1968.890 us; speedup 1.0000x reference)
//
#include <hip/hip_runtime.h>

// RegressiveAutoEncoder B=2048,T=512,F=8,H=128 — MFMA v8 (2 blocks/CU, fat waves).
// 512 blocks x 256 threads (4 waves), BT=4 batch rows/block, launch_bounds(256,2)
// -> 2 independent blocks per CU: their barriers interleave and fill the ~37%
// barrier-drain idle seen at 1 block/CU (v5). Per-wave footprint ~245 VGPR
// (fits the 256 cap — R6's spill was a 64-reg cap, R7's serialization was
// doubled work at 1 block/CU).
// Wave w owns H-cols [w*32,w*32+32) of EACH gate -> 8 N-tiles, B1=5x8 frags
// register-resident. Single MFMA pass (40/wave/step): U,h = rtn-bf16
// (v6-validated); x/y hi+lo k-slots 128..143 vs rtn-W; bias k-slot 16.
// Redistribute per gate-half: shfl_xor 16/32/48 + select; 2 cells/lane.
// One barrier/step; h/x dbuf by parity; dense redundant/wave, dup Wout cols.

namespace {

typedef __attribute__((ext_vector_type(8))) short bf16x8;
typedef __attribute__((ext_vector_type(4))) float f32x4;

constexpr int T = 512, F = 8, H = 128, G4 = 512, NTH = 256, BT = 4;
constexpr int HS = 136;  // shorts per hb row (272B, b128-aligned, 2-way-free)
constexpr int XS = 32;   // shorts per xp row: [xhi 0..7 | xlo 8..15 | 1.0 @16 | 0]

struct __align__(16) Smem {
  unsigned short hb[2][BT][HS];  // h rtn-bf16, A-layout, dbuf by step parity
  unsigned short xp[2][BT][XS];  // input (x_t / y_{t-1}) hi|lo|bias-one, dbuf
};

__device__ __forceinline__ float rcpf(float v) { return __builtin_amdgcn_rcpf(v); }
__device__ __forceinline__ float sigm(float v) { return rcpf(1.0f + __expf(-v)); }
__device__ __forceinline__ float tanh_(float v) { return 1.0f - 2.0f * rcpf(__expf(2.0f * v) + 1.0f); }

__device__ __forceinline__ unsigned short bf_rtn(float v) {
  unsigned u = __float_as_uint(v);
  return (unsigned short)((u + 0x7FFFu + ((u >> 16) & 1u)) >> 16);
}
__device__ __forceinline__ void split_tr(float v, unsigned short& hi, unsigned short& lo) {
  unsigned u = __float_as_uint(v);
  hi = (unsigned short)(u >> 16);
  lo = bf_rtn(v - __uint_as_float(u & 0xFFFF0000u));
}

__global__ __launch_bounds__(NTH, 2)
void rae_v8(const float* __restrict__ x,
            const float* __restrict__ Wenc, const float* __restrict__ Uenc, const float* __restrict__ benc,
            const float* __restrict__ Wdec, const float* __restrict__ Udec, const float* __restrict__ bdec,
            const float* __restrict__ Wout, const float* __restrict__ boutg,
            float* __restrict__ out)
{
  __shared__ Smem s;
  const int tid = threadIdx.x, lane = tid & 63, w = tid >> 6;   // w = 0..3
  const int q = lane >> 4, n = lane & 15;
  const long gb = (long)blockIdx.x * BT;

  for (int i = tid; i < 2 * BT * HS; i += NTH) (&s.hb[0][0][0])[i] = 0;
  for (int i = tid; i < 2 * BT * XS; i += NTH) (&s.xp[0][0][0])[i] = 0;
  __syncthreads();
  if (tid < 32) {  // stage x_0: r = tid>>3 (0..3), f = tid&7
    unsigned short hv, lv;
    split_tr(x[(gb + (tid >> 3)) * (long)(T * F) + (tid & 7)], hv, lv);
    s.xp[0][tid >> 3][tid & 7] = hv;
    s.xp[0][tid >> 3][(tid & 7) + 8] = lv;
  }
  if (tid < 8) s.xp[tid >> 2][tid & 3][16] = 0x3F80;  // bf16(1.0) bias slot, both parities
  const float boutr = boutg[n & 7];
  float cstA = 0.f, cstB = 0.f;  // cells (row q, col w*32+n) and (row q, col w*32+16+n)
  __syncthreads();

  bf16x8 A[5];
  {
    bf16x8 zz = {0, 0, 0, 0, 0, 0, 0, 0};
#pragma unroll
    for (int kt = 0; kt < 5; ++kt) A[kt] = zz;  // h_0 = 0; lanes n>=4 keep zeros forever
  }

  bf16x8 B1[5][8];   // 160 VGPRs, the per-wave U|W|bias panel
  bf16x8 Bw[4];      // dense Wout (cols duplicated: n and n^8 identical)

  for (int ph = 0; ph < 2; ++ph) {
    const float* U  = ph ? Udec : Uenc;
    const float* W  = ph ? Wdec : Wenc;
    const float* bi = ph ? bdec : benc;

    // ---- B preload: tile tl = g*2+half -> col g*128 + w*32 + half*16 + n.
    // kt<4 = rtn(U); kt=4 k-slots: 0..7 W(x_hi), 8..15 W(x_lo), 16 bias, rest 0.
#pragma unroll
    for (int kt = 0; kt < 5; ++kt)
#pragma unroll
      for (int tl = 0; tl < 8; ++tl) {
        const int col = (tl >> 1) * 128 + w * 32 + (tl & 1) * 16 + n;
        bf16x8 b1;
#pragma unroll
        for (int j = 0; j < 8; ++j) {
          unsigned short v = 0;
          if (kt < 4) {
            v = bf_rtn(U[(kt * 32 + q * 8 + j) * G4 + col]);
          } else {
            const int kk = q * 8 + j;
            if (kk < 16)       v = bf_rtn(W[(kk & 7) * G4 + col]);
            else if (kk == 16) v = bf_rtn(bi[col]);
          }
          b1[j] = (short)v;
        }
        B1[kt][tl] = b1;
      }

    if (ph == 1) {
#pragma unroll
      for (int kt = 0; kt < 4; ++kt) {
        bf16x8 bw;
#pragma unroll
        for (int j = 0; j < 8; ++j)
          bw[j] = (short)bf_rtn(Wout[(kt * 32 + q * 8 + j) * F + (n & 7)]);
        Bw[kt] = bw;
      }
      if (tid < 32) {  // y_{-1} = x[:,T-1,:] into parity slot 0
        unsigned short hv, lv;
        split_tr(x[(gb + (tid >> 3)) * (long)(T * F) + (T - 1) * F + (tid & 7)], hv, lv);
        s.xp[0][tid >> 3][tid & 7] = hv;
        s.xp[0][tid >> 3][(tid & 7) + 8] = lv;
      }
      __syncthreads();
    }

    for (int t = 0; t < T; ++t) {
      const int pcur = t & 1, pnxt = (t + 1) & 1;
      float xnext = 0.f;
      if (ph == 0 && tid < 32 && t + 1 < T)
        xnext = x[(gb + (tid >> 3)) * (long)(T * F) + (t + 1) * F + (tid & 7)];

      if (n < BT) A[4] = *(const bf16x8*)&s.xp[pcur][n][q * 8];

      // ---- MFMA: 5 ksteps x 8 tiles, 8 independent chains ----
      f32x4 acc[8];
#pragma unroll
      for (int tl = 0; tl < 8; ++tl) acc[tl] = f32x4{0.f, 0.f, 0.f, 0.f};
#pragma unroll
      for (int kt = 0; kt < 5; ++kt)
#pragma unroll
        for (int tl = 0; tl < 8; ++tl)
          acc[tl] = __builtin_amdgcn_mfma_f32_16x16x32_bf16(A[kt], B1[kt][tl], acc[tl], 0, 0, 0);

      // ---- redistribute: lane (q,n) takes C row q from lane (0,n) ----
      float zA[4], zB[4];
#pragma unroll
      for (int g = 0; g < 4; ++g) {
        {
          const f32x4 a = acc[2 * g];
          float s1 = __shfl_xor(a[1], 16, 64);
          float s2 = __shfl_xor(a[2], 32, 64);
          float s3 = __shfl_xor(a[3], 48, 64);
          zA[g] = (q == 0) ? a[0] : (q == 1) ? s1 : (q == 2) ? s2 : s3;
        }
        {
          const f32x4 a = acc[2 * g + 1];
          float s1 = __shfl_xor(a[1], 16, 64);
          float s2 = __shfl_xor(a[2], 32, 64);
          float s3 = __shfl_xor(a[3], 48, 64);
          zB[g] = (q == 0) ? a[0] : (q == 1) ? s1 : (q == 2) ? s2 : s3;
        }
      }
      // ---- cell update: 2 cells/lane (row q; cols w*32+n, w*32+16+n) ----
      cstA = sigm(zA[1]) * cstA + sigm(zA[0]) * tanh_(zA[2]);
      cstB = sigm(zB[1]) * cstB + sigm(zB[0]) * tanh_(zB[2]);
      const float hA = sigm(zA[3]) * tanh_(cstA);
      const float hB = sigm(zB[3]) * tanh_(cstB);
      s.hb[pnxt][q][w * 32 + n]      = bf_rtn(hA);
      s.hb[pnxt][q][w * 32 + 16 + n] = bf_rtn(hB);

      if (ph == 0 && tid < 32 && t + 1 < T) {
        unsigned short hv, lv; split_tr(xnext, hv, lv);
        s.xp[pnxt][tid >> 3][tid & 7] = hv;
        s.xp[pnxt][tid >> 3][(tid & 7) + 8] = lv;
      }
      __syncthreads();  // the only barrier per step

      // h fragments for next iter / dense (masked to valid rows)
      if (n < BT) {
#pragma unroll
        for (int kt = 0; kt < 4; ++kt)
          A[kt] = *(const bf16x8*)&s.hb[pnxt][n][kt * 32 + q * 8];
      }

      if (ph == 1) {
        // dense y = relu(h@Wout + b), redundant per wave (4 MFMAs)
        f32x4 ay = {0.f, 0.f, 0.f, 0.f};
#pragma unroll
        for (int kt = 0; kt < 4; ++kt)
          ay = __builtin_amdgcn_mfma_f32_16x16x32_bf16(A[kt], Bw[kt], ay, 0, 0, 0);
        float y[4];
#pragma unroll
        for (int p = 0; p < 4; ++p)
          y[p] = fmaxf(ay[p] + boutr, 0.f);
        if (q == 0 && n < 8) {                 // rows p=0..3, col f=n
          if (w == 0) {
#pragma unroll
            for (int p = 0; p < 4; ++p)
              out[((gb + p) * T + t) * F + n] = y[p];
          }
#pragma unroll
          for (int p = 0; p < 4; ++p) {        // idempotent full-precision feedback
            unsigned short hv, lv; split_tr(y[p], hv, lv);
            s.xp[pnxt][p][n]     = hv;
            s.xp[pnxt][p][n + 8] = lv;
          }
        }
      }
    }
  }
}

} // namespace

extern "C" void kernel_launch(void* const* d_in, const int* in_sizes, int n_in,
                              void* d_out, int out_size, void* d_ws, size_t ws_size,
                              hipStream_t stream) {
  const float* x    = (const float*)d_in[0];
  const float* Wenc = (const float*)d_in[1];
  const float* Uenc = (const float*)d_in[2];
  const float* benc = (const float*)d_in[3];
  const float* Wdec = (const float*)d_in[4];
  const float* Udec = (const float*)d_in[5];
  const float* bdec = (const float*)d_in[6];
  const float* Wout = (const float*)d_in[7];
  const float* bout = (const float*)d_in[8];
  float* out = (float*)d_out;

  const int Bsz = in_sizes[0] / (T * F);  // 2048
  const int nblocks = Bsz / BT;           // 512 -> 2 blocks/CU
  rae_v8<<<dim3(nblocks), dim3(NTH), 0, stream>>>(
      x, Wenc, Uenc, benc, Wdec, Udec, bdec, Wout, bout, out);
}

// Round 9
// 1850.339 us; speedup vs baseline: 1.0641x; 1.0641x over previous
//
#include <hip/hip_runtime.h>

// RegressiveAutoEncoder B=2048,T=512,F=8,H=128 — MFMA v9 (2 blocks/CU, no-spill).
// 512 blocks x 256 threads (4 waves), BT=4 rows/block, launch_bounds(256,2)
// -> 2 independent blocks/CU; their barriers interleave to fill the ~37%
// barrier-drain idle measured at 1 block/CU (v5).
// v8 retry with the register peak cut below the 256/wave unified cap:
// dense Wout panel moved from 16 resident VGPRs to LDS (pre-formatted
// B-fragments, 4 ds_read_b128 per decoder step). Peak live ~225 regs.
// Wave w owns H-cols [w*32,w*32+32) of each gate -> 8 N-tiles, B1[5][8]=160
// VGPRs register-resident. Single MFMA pass: U,h = rtn-bf16 (v6-validated);
// x/y full precision via hi+lo k-slots 128..143 vs rtn-W; bias k-slot 16.
// Redistribute: lane(q,n) takes C row q from lane(0,n) via shfl_xor 16/32/48.
// One barrier/step; h/x dbuf by step parity; dense redundant per wave with
// idempotent feedback writes (intra-wave program order makes it race-free).

namespace {

typedef __attribute__((ext_vector_type(8))) short bf16x8;
typedef __attribute__((ext_vector_type(4))) float f32x4;

constexpr int T = 512, F = 8, H = 128, G4 = 512, NTH = 256, BT = 4;
constexpr int HS = 136;  // shorts per hb row (272B, b128-aligned)
constexpr int XS = 32;   // shorts per xp row: [xhi 0..7 | xlo 8..15 | 1.0 @16 | 0]

struct __align__(16) Smem {
  unsigned short hb[2][BT][HS];   // h rtn-bf16, A-layout, dbuf by step parity
  unsigned short xp[2][BT][XS];   // input (x_t / y_{t-1}) hi|lo|bias-one, dbuf
  unsigned short woutl[4][64][8]; // Wout B-frags: [kt][lane][j], b128 per lane
};

__device__ __forceinline__ float rcpf(float v) { return __builtin_amdgcn_rcpf(v); }
__device__ __forceinline__ float sigm(float v) { return rcpf(1.0f + __expf(-v)); }
__device__ __forceinline__ float tanh_(float v) { return 1.0f - 2.0f * rcpf(__expf(2.0f * v) + 1.0f); }

__device__ __forceinline__ unsigned short bf_rtn(float v) {
  unsigned u = __float_as_uint(v);
  return (unsigned short)((u + 0x7FFFu + ((u >> 16) & 1u)) >> 16);
}
__device__ __forceinline__ void split_tr(float v, unsigned short& hi, unsigned short& lo) {
  unsigned u = __float_as_uint(v);
  hi = (unsigned short)(u >> 16);
  lo = bf_rtn(v - __uint_as_float(u & 0xFFFF0000u));
}

__global__ __launch_bounds__(NTH, 2)
void rae_v9(const float* __restrict__ x,
            const float* __restrict__ Wenc, const float* __restrict__ Uenc, const float* __restrict__ benc,
            const float* __restrict__ Wdec, const float* __restrict__ Udec, const float* __restrict__ bdec,
            const float* __restrict__ Wout, const float* __restrict__ boutg,
            float* __restrict__ out)
{
  __shared__ Smem s;
  const int tid = threadIdx.x, lane = tid & 63, w = tid >> 6;   // w = 0..3
  const int q = lane >> 4, n = lane & 15;
  const long gb = (long)blockIdx.x * BT;

  for (int i = tid; i < 2 * BT * HS; i += NTH) (&s.hb[0][0][0])[i] = 0;
  for (int i = tid; i < 2 * BT * XS; i += NTH) (&s.xp[0][0][0])[i] = 0;
  __syncthreads();
  if (tid < 32) {  // stage x_0: r = tid>>3 (0..3), f = tid&7
    unsigned short hv, lv;
    split_tr(x[(gb + (tid >> 3)) * (long)(T * F) + (tid & 7)], hv, lv);
    s.xp[0][tid >> 3][tid & 7] = hv;
    s.xp[0][tid >> 3][(tid & 7) + 8] = lv;
  }
  if (tid < 8) s.xp[tid >> 2][tid & 3][16] = 0x3F80;  // bf16(1.0) bias slot, both parities
  if (tid < 64) {  // stage Wout B-frags once: lane-indexed, shared by all waves
    const int qt = tid >> 4, nt = tid & 15;
#pragma unroll
    for (int kt = 0; kt < 4; ++kt)
#pragma unroll
      for (int j = 0; j < 8; ++j)
        s.woutl[kt][tid][j] = bf_rtn(Wout[(kt * 32 + qt * 8 + j) * F + (nt & 7)]);
  }
  const float boutr = boutg[n & 7];
  float cstA = 0.f, cstB = 0.f;  // cells (row q, col w*32+n) and (row q, col w*32+16+n)
  __syncthreads();

  bf16x8 A[5];
  {
    bf16x8 zz = {0, 0, 0, 0, 0, 0, 0, 0};
#pragma unroll
    for (int kt = 0; kt < 5; ++kt) A[kt] = zz;  // h_0 = 0; lanes n>=4 keep zeros forever
  }

  bf16x8 B1[5][8];   // 160 VGPRs: per-wave U|W|bias panel (the only resident panel)

  for (int ph = 0; ph < 2; ++ph) {
    const float* U  = ph ? Udec : Uenc;
    const float* W  = ph ? Wdec : Wenc;
    const float* bi = ph ? bdec : benc;

    // ---- B preload: tile tl -> col (tl>>1)*128 + w*32 + (tl&1)*16 + n.
    // kt<4 = rtn(U); kt=4 k-slots: 0..7 W(x_hi), 8..15 W(x_lo), 16 bias, rest 0.
#pragma unroll
    for (int kt = 0; kt < 5; ++kt)
#pragma unroll
      for (int tl = 0; tl < 8; ++tl) {
        const int col = (tl >> 1) * 128 + w * 32 + (tl & 1) * 16 + n;
        bf16x8 b1;
#pragma unroll
        for (int j = 0; j < 8; ++j) {
          unsigned short v = 0;
          if (kt < 4) {
            v = bf_rtn(U[(kt * 32 + q * 8 + j) * G4 + col]);
          } else {
            const int kk = q * 8 + j;
            if (kk < 16)       v = bf_rtn(W[(kk & 7) * G4 + col]);
            else if (kk == 16) v = bf_rtn(bi[col]);
          }
          b1[j] = (short)v;
        }
        B1[kt][tl] = b1;
      }

    if (ph == 1) {
      if (tid < 32) {  // y_{-1} = x[:,T-1,:] into parity slot 0
        unsigned short hv, lv;
        split_tr(x[(gb + (tid >> 3)) * (long)(T * F) + (T - 1) * F + (tid & 7)], hv, lv);
        s.xp[0][tid >> 3][tid & 7] = hv;
        s.xp[0][tid >> 3][(tid & 7) + 8] = lv;
      }
      __syncthreads();
    }

    for (int t = 0; t < T; ++t) {
      const int pcur = t & 1, pnxt = (t + 1) & 1;
      float xnext = 0.f;
      if (ph == 0 && tid < 32 && t + 1 < T)
        xnext = x[(gb + (tid >> 3)) * (long)(T * F) + (t + 1) * F + (tid & 7)];

      if (n < BT) A[4] = *(const bf16x8*)&s.xp[pcur][n][q * 8];

      // ---- MFMA: 5 ksteps x 8 tiles ----
      f32x4 acc[8];
#pragma unroll
      for (int tl = 0; tl < 8; ++tl) acc[tl] = f32x4{0.f, 0.f, 0.f, 0.f};
#pragma unroll
      for (int kt = 0; kt < 5; ++kt)
#pragma unroll
        for (int tl = 0; tl < 8; ++tl)
          acc[tl] = __builtin_amdgcn_mfma_f32_16x16x32_bf16(A[kt], B1[kt][tl], acc[tl], 0, 0, 0);

      // ---- redistribute: lane (q,n) takes C row q from lane (0,n) ----
      float zA[4], zB[4];
#pragma unroll
      for (int g = 0; g < 4; ++g) {
        {
          const f32x4 a = acc[2 * g];
          float s1 = __shfl_xor(a[1], 16, 64);
          float s2 = __shfl_xor(a[2], 32, 64);
          float s3 = __shfl_xor(a[3], 48, 64);
          zA[g] = (q == 0) ? a[0] : (q == 1) ? s1 : (q == 2) ? s2 : s3;
        }
        {
          const f32x4 a = acc[2 * g + 1];
          float s1 = __shfl_xor(a[1], 16, 64);
          float s2 = __shfl_xor(a[2], 32, 64);
          float s3 = __shfl_xor(a[3], 48, 64);
          zB[g] = (q == 0) ? a[0] : (q == 1) ? s1 : (q == 2) ? s2 : s3;
        }
      }
      // ---- cell update: 2 cells/lane (row q; cols w*32+n, w*32+16+n) ----
      cstA = sigm(zA[1]) * cstA + sigm(zA[0]) * tanh_(zA[2]);
      cstB = sigm(zB[1]) * cstB + sigm(zB[0]) * tanh_(zB[2]);
      const float hA = sigm(zA[3]) * tanh_(cstA);
      const float hB = sigm(zB[3]) * tanh_(cstB);
      s.hb[pnxt][q][w * 32 + n]      = bf_rtn(hA);
      s.hb[pnxt][q][w * 32 + 16 + n] = bf_rtn(hB);

      if (ph == 0 && tid < 32 && t + 1 < T) {
        unsigned short hv, lv; split_tr(xnext, hv, lv);
        s.xp[pnxt][tid >> 3][tid & 7] = hv;
        s.xp[pnxt][tid >> 3][(tid & 7) + 8] = lv;
      }
      __syncthreads();  // the only barrier per step

      // h fragments for next iter / dense (masked to valid rows)
      if (n < BT) {
#pragma unroll
        for (int kt = 0; kt < 4; ++kt)
          A[kt] = *(const bf16x8*)&s.hb[pnxt][n][kt * 32 + q * 8];
      }

      if (ph == 1) {
        // dense y = relu(h@Wout + b), redundant per wave; Wout frags from LDS
        f32x4 ay = {0.f, 0.f, 0.f, 0.f};
#pragma unroll
        for (int kt = 0; kt < 4; ++kt) {
          const bf16x8 bw = *(const bf16x8*)&s.woutl[kt][lane][0];
          ay = __builtin_amdgcn_mfma_f32_16x16x32_bf16(A[kt], bw, ay, 0, 0, 0);
        }
        float y[4];
#pragma unroll
        for (int p = 0; p < 4; ++p)
          y[p] = fmaxf(ay[p] + boutr, 0.f);
        if (q == 0 && n < 8) {                 // rows p=0..3, col f=n
          if (w == 0) {
#pragma unroll
            for (int p = 0; p < 4; ++p)
              out[((gb + p) * T + t) * F + n] = y[p];
          }
#pragma unroll
          for (int p = 0; p < 4; ++p) {        // idempotent full-precision feedback
            unsigned short hv, lv; split_tr(y[p], hv, lv);
            s.xp[pnxt][p][n]     = hv;
            s.xp[pnxt][p][n + 8] = lv;
          }
        }
      }
    }
  }
}

} // namespace

extern "C" void kernel_launch(void* const* d_in, const int* in_sizes, int n_in,
                              void* d_out, int out_size, void* d_ws, size_t ws_size,
                              hipStream_t stream) {
  const float* x    = (const float*)d_in[0];
  const float* Wenc = (const float*)d_in[1];
  const float* Uenc = (const float*)d_in[2];
  const float* benc = (const float*)d_in[3];
  const float* Wdec = (const float*)d_in[4];
  const float* Udec = (const float*)d_in[5];
  const float* bdec = (const float*)d_in[6];
  const float* Wout = (const float*)d_in[7];
  const float* bout = (const float*)d_in[8];
  float* out = (float*)d_out;

  const int Bsz = in_sizes[0] / (T * F);  // 2048
  const int nblocks = Bsz / BT;           // 512 -> 2 blocks/CU
  rae_v9<<<dim3(nblocks), dim3(NTH), 0, stream>>>(
      x, Wenc, Uenc, benc, Wdec, Udec, bdec, Wout, bout, out);
}